// Round 5
// baseline (165.324 us; speedup 1.0000x reference)
//
#include <hip/hip_runtime.h>
#include <math.h>

// Sizes fixed by the problem: B=2, T=512, E=384, H=64, dk=6.
#define SEQ_T   512
#define E_DIM   384
#define H_NUM   64
#define DKQ     6
#define NROWS   1024              // B*T
#define QKV_ELEMS (NROWS*E_DIM)   // 393216 floats per tensor

// ---------------------------------------------------------------------------
// Quantum layer, analytic form (re-verified via Bloch algebra + Heisenberg
// push of Z through the CNOT ring):
//   z_i = cos(a_i)cos(b_i)*cos(x_i) - sin(b_i)*sin(x_i)
//   o0 = z1 z2 z3 z4 z5 ; o1 = z0 z1 ; o_k = o_{k-1} * z_k  (k=2..5)
// ---------------------------------------------------------------------------
__device__ __forceinline__ void qmap6(const float* __restrict__ in,
                                      const float* __restrict__ AB,
                                      float* __restrict__ out)
{
    float z[6];
#pragma unroll
    for (int i = 0; i < 6; ++i) {
        float s, c;
        sincosf(in[i], &s, &c);
        z[i] = AB[i] * c - AB[6 + i] * s;
    }
    float z01 = z[0] * z[1];
    float z12 = z[1] * z[2];
    float z34 = z[3] * z[4];
    out[0] = z12 * z34 * z[5];
    out[1] = z01;
    out[2] = z01 * z[2];
    out[3] = out[2] * z[3];
    out[4] = out[3] * z[4];
    out[5] = out[4] * z[5];
}

// ---------------------------------------------------------------------------
// Kernel A: Y = x @ [Wq;Wk;Wv]^T + bias, scattered to (B,H,T,dk) buffers.
// 64x64 tile, K-chunks of 64, 256 threads, 4x4 micro-tile.
// grid: (1024/64, 1152/64) = (16, 18)
// ---------------------------------------------------------------------------
__global__ __launch_bounds__(256)
void qkv_gemm(const float* __restrict__ x,
              const float* __restrict__ Wq, const float* __restrict__ bq,
              const float* __restrict__ Wk, const float* __restrict__ bk,
              const float* __restrict__ Wv, const float* __restrict__ bv,
              float* __restrict__ qb, float* __restrict__ kb, float* __restrict__ vb)
{
    __shared__ float xs[64][65];
    __shared__ float ws[64][65];
    const int tid = threadIdx.x;
    const int tx = tid & 15;
    const int ty = tid >> 4;
    const int n0 = blockIdx.x * 64;
    const int j0 = blockIdx.y * 64;

    const float* W; const float* bias; float* ob; int e0;
    if (j0 < 384)      { W = Wq; bias = bq; ob = qb; e0 = j0; }
    else if (j0 < 768) { W = Wk; bias = bk; ob = kb; e0 = j0 - 384; }
    else               { W = Wv; bias = bv; ob = vb; e0 = j0 - 768; }

    float acc[4][4];
#pragma unroll
    for (int i = 0; i < 4; ++i)
#pragma unroll
        for (int j = 0; j < 4; ++j) acc[i][j] = 0.f;

    const int lrow = tid >> 4;          // 0..15
    const int lk   = (tid & 15) << 2;   // 0,4,...,60

    for (int kc = 0; kc < E_DIM; kc += 64) {
#pragma unroll
        for (int rr = 0; rr < 4; ++rr) {
            const int row = lrow + rr * 16;
            float4 xv = *reinterpret_cast<const float4*>(x + (size_t)(n0 + row) * E_DIM + kc + lk);
            xs[row][lk + 0] = xv.x; xs[row][lk + 1] = xv.y;
            xs[row][lk + 2] = xv.z; xs[row][lk + 3] = xv.w;
            float4 wv = *reinterpret_cast<const float4*>(W + (size_t)(e0 + row) * E_DIM + kc + lk);
            ws[row][lk + 0] = wv.x; ws[row][lk + 1] = wv.y;
            ws[row][lk + 2] = wv.z; ws[row][lk + 3] = wv.w;
        }
        __syncthreads();
#pragma unroll 8
        for (int kk = 0; kk < 64; ++kk) {
            float a0 = xs[ty * 4 + 0][kk], a1 = xs[ty * 4 + 1][kk];
            float a2 = xs[ty * 4 + 2][kk], a3 = xs[ty * 4 + 3][kk];
            float b0 = ws[tx * 4 + 0][kk], b1 = ws[tx * 4 + 1][kk];
            float b2 = ws[tx * 4 + 2][kk], b3 = ws[tx * 4 + 3][kk];
            acc[0][0] += a0 * b0; acc[0][1] += a0 * b1; acc[0][2] += a0 * b2; acc[0][3] += a0 * b3;
            acc[1][0] += a1 * b0; acc[1][1] += a1 * b1; acc[1][2] += a1 * b2; acc[1][3] += a1 * b3;
            acc[2][0] += a2 * b0; acc[2][1] += a2 * b1; acc[2][2] += a2 * b2; acc[2][3] += a2 * b3;
            acc[3][0] += a3 * b0; acc[3][1] += a3 * b1; acc[3][2] += a3 * b2; acc[3][3] += a3 * b3;
        }
        __syncthreads();
    }

    // Epilogue: scatter to (B,H,T,dk): idx = ((b*64+h)*512 + t)*6 + d
#pragma unroll
    for (int i = 0; i < 4; ++i) {
        const int n = n0 + ty * 4 + i;     // b*512 + t
        const int b = n >> 9;
        const int t = n & 511;
#pragma unroll
        for (int j = 0; j < 4; ++j) {
            const int e = e0 + tx * 4 + j; // 0..383
            const int h = e / 6;
            const int d = e - h * 6;
            const float v = acc[i][j] + bias[e];
            ob[(((size_t)(b * H_NUM + h) * SEQ_T) + t) * DKQ + d] = v;
        }
    }
}

// ---------------------------------------------------------------------------
// Kernel B: attention per (b,h). K/V quantum-mapped into packed LDS
// kv[s] = {k0..k5, v0..v5}; one q-row per thread; single-pass softmax
// (|score| <= sqrt(6) -> no max subtraction needed).
// Inner loop: 3 uniform-address ds_read_b128 per s (broadcast, conflict-free).
// grid: (B*H = 128, 2 chunks of 256 q-rows), block 256.
// ---------------------------------------------------------------------------
__global__ __launch_bounds__(256)
void attn_kernel(const float* __restrict__ qb,
                 const float* __restrict__ kb,
                 const float* __restrict__ vb,
                 const float* __restrict__ qparams,
                 float* __restrict__ merged)
{
    // 16B-aligned so float4 (ds_*_b128) access is legal.
    __shared__ __align__(16) float kv[SEQ_T][12];   // 24 KB

    const int bh  = blockIdx.x;       // b*64 + h
    const int tid = threadIdx.x;

    // Per-thread qparam constants (12 trig ops; avoids an LDS+barrier dep)
    float AB[12];
#pragma unroll
    for (int i = 0; i < 6; ++i) {
        const float a = qparams[i * 2 + 0];
        const float b = qparams[i * 2 + 1];
        AB[i]     = cosf(a) * cosf(b);
        AB[6 + i] = sinf(b);
    }

    const float* Kp = kb + (size_t)bh * SEQ_T * DKQ;
    const float* Vp = vb + (size_t)bh * SEQ_T * DKQ;

    // Load Q early (independent of staging below).
    const int t = blockIdx.y * 256 + tid;  // q row in [0,512)
    float qin[6];
    const float* Qp = qb + ((size_t)bh * SEQ_T + t) * DKQ;
#pragma unroll
    for (int i = 0; i < 6; ++i) qin[i] = Qp[i];

    // Stage K/V rows 2p, 2p+1 per thread (aligned float4 global reads).
    {
        const int p = tid;  // 0..255  -> rows 2p, 2p+1
        const float4* K4 = reinterpret_cast<const float4*>(Kp);
        const float4* V4 = reinterpret_cast<const float4*>(Vp);
        float4 ka = K4[3 * p + 0], kbv = K4[3 * p + 1], kc = K4[3 * p + 2];
        float4 va = V4[3 * p + 0], vbv = V4[3 * p + 1], vc = V4[3 * p + 2];

        float in0[6] = {ka.x, ka.y, ka.z, ka.w, kbv.x, kbv.y};
        float in1[6] = {kbv.z, kbv.w, kc.x, kc.y, kc.z, kc.w};
        float iv0[6] = {va.x, va.y, va.z, va.w, vbv.x, vbv.y};
        float iv1[6] = {vbv.z, vbv.w, vc.x, vc.y, vc.z, vc.w};
        float ok0[6], ok1[6], ov0[6], ov1[6];
        qmap6(in0, AB, ok0); qmap6(in1, AB, ok1);
        qmap6(iv0, AB, ov0); qmap6(iv1, AB, ov1);

        float4* kv4 = reinterpret_cast<float4*>(&kv[0][0]);
        kv4[3 * (2 * p) + 0] = make_float4(ok0[0], ok0[1], ok0[2], ok0[3]);
        kv4[3 * (2 * p) + 1] = make_float4(ok0[4], ok0[5], ov0[0], ov0[1]);
        kv4[3 * (2 * p) + 2] = make_float4(ov0[2], ov0[3], ov0[4], ov0[5]);
        kv4[3 * (2 * p + 1) + 0] = make_float4(ok1[0], ok1[1], ok1[2], ok1[3]);
        kv4[3 * (2 * p + 1) + 1] = make_float4(ok1[4], ok1[5], ov1[0], ov1[1]);
        kv4[3 * (2 * p + 1) + 2] = make_float4(ov1[2], ov1[3], ov1[4], ov1[5]);
    }
    __syncthreads();

    float qrow[6];
    qmap6(qin, AB, qrow);
    const float inv_sqrt_dk = 0.40824829046386296f;  // 1/sqrt(6)
#pragma unroll
    for (int i = 0; i < 6; ++i) qrow[i] *= inv_sqrt_dk;

    float accv[6] = {0.f, 0.f, 0.f, 0.f, 0.f, 0.f};
    float denom = 0.f;

    const float4* kv4 = reinterpret_cast<const float4*>(&kv[0][0]);
#pragma unroll 4
    for (int s = 0; s < SEQ_T; ++s) {
        const float4 r0 = kv4[3 * s + 0];   // k0..k3
        const float4 r1 = kv4[3 * s + 1];   // k4,k5,v0,v1
        const float4 r2 = kv4[3 * s + 2];   // v2..v5
        const float sc = qrow[0] * r0.x + qrow[1] * r0.y + qrow[2] * r0.z
                       + qrow[3] * r0.w + qrow[4] * r1.x + qrow[5] * r1.y;
        const float e = __expf(sc);
        denom += e;
        accv[0] += e * r1.z; accv[1] += e * r1.w;
        accv[2] += e * r2.x; accv[3] += e * r2.y;
        accv[4] += e * r2.z; accv[5] += e * r2.w;
    }

    const float r = 1.0f / denom;
    const int b = bh >> 6;
    const int h = bh & 63;
    float* mp = merged + ((size_t)(b * SEQ_T + t)) * E_DIM + h * DKQ;
#pragma unroll
    for (int d = 0; d < 6; ++d) mp[d] = accv[d] * r;
}

// ---------------------------------------------------------------------------
// Kernel C: out = merged @ Wo^T + bo   (1024 x 384 x 384), coalesced write.
// grid: (16, 6)
// ---------------------------------------------------------------------------
__global__ __launch_bounds__(256)
void out_gemm(const float* __restrict__ merged,
              const float* __restrict__ Wo, const float* __restrict__ bo,
              float* __restrict__ out)
{
    __shared__ float xs[64][65];
    __shared__ float ws[64][65];
    const int tid = threadIdx.x;
    const int tx = tid & 15;
    const int ty = tid >> 4;
    const int n0 = blockIdx.x * 64;
    const int e0 = blockIdx.y * 64;

    float acc[4][4];
#pragma unroll
    for (int i = 0; i < 4; ++i)
#pragma unroll
        for (int j = 0; j < 4; ++j) acc[i][j] = 0.f;

    const int lrow = tid >> 4;
    const int lk   = (tid & 15) << 2;

    for (int kc = 0; kc < E_DIM; kc += 64) {
#pragma unroll
        for (int rr = 0; rr < 4; ++rr) {
            const int row = lrow + rr * 16;
            float4 xv = *reinterpret_cast<const float4*>(merged + (size_t)(n0 + row) * E_DIM + kc + lk);
            xs[row][lk + 0] = xv.x; xs[row][lk + 1] = xv.y;
            xs[row][lk + 2] = xv.z; xs[row][lk + 3] = xv.w;
            float4 wv = *reinterpret_cast<const float4*>(Wo + (size_t)(e0 + row) * E_DIM + kc + lk);
            ws[row][lk + 0] = wv.x; ws[row][lk + 1] = wv.y;
            ws[row][lk + 2] = wv.z; ws[row][lk + 3] = wv.w;
        }
        __syncthreads();
#pragma unroll 8
        for (int kk = 0; kk < 64; ++kk) {
            float a0 = xs[ty * 4 + 0][kk], a1 = xs[ty * 4 + 1][kk];
            float a2 = xs[ty * 4 + 2][kk], a3 = xs[ty * 4 + 3][kk];
            float b0 = ws[tx * 4 + 0][kk], b1 = ws[tx * 4 + 1][kk];
            float b2 = ws[tx * 4 + 2][kk], b3 = ws[tx * 4 + 3][kk];
            acc[0][0] += a0 * b0; acc[0][1] += a0 * b1; acc[0][2] += a0 * b2; acc[0][3] += a0 * b3;
            acc[1][0] += a1 * b0; acc[1][1] += a1 * b1; acc[1][2] += a1 * b2; acc[1][3] += a1 * b3;
            acc[2][0] += a2 * b0; acc[2][1] += a2 * b1; acc[2][2] += a2 * b2; acc[2][3] += a2 * b3;
            acc[3][0] += a3 * b0; acc[3][1] += a3 * b1; acc[3][2] += a3 * b2; acc[3][3] += a3 * b3;
        }
        __syncthreads();
    }

#pragma unroll
    for (int i = 0; i < 4; ++i) {
        const int n = n0 + ty * 4 + i;
#pragma unroll
        for (int j = 0; j < 4; ++j) {
            const int e = e0 + tx * 4 + j;
            out[(size_t)n * E_DIM + e] = acc[i][j] + bo[e];
        }
    }
}

// ---------------------------------------------------------------------------
extern "C" void kernel_launch(void* const* d_in, const int* in_sizes, int n_in,
                              void* d_out, int out_size, void* d_ws, size_t ws_size,
                              hipStream_t stream)
{
    const float* x  = (const float*)d_in[0];
    const float* Wq = (const float*)d_in[1];
    const float* bq = (const float*)d_in[2];
    const float* Wk = (const float*)d_in[3];
    const float* bk = (const float*)d_in[4];
    const float* Wv = (const float*)d_in[5];
    const float* bv = (const float*)d_in[6];
    const float* Wo = (const float*)d_in[7];
    const float* bo = (const float*)d_in[8];
    const float* qp = (const float*)d_in[9];
    float* out = (float*)d_out;

    float* qb     = (float*)d_ws;
    float* kb     = qb + QKV_ELEMS;
    float* vb     = kb + QKV_ELEMS;
    float* merged = vb + QKV_ELEMS;   // total 4 * 1.5 MB = 6.3 MB of d_ws

    qkv_gemm<<<dim3(16, 18), 256, 0, stream>>>(x, Wq, bq, Wk, bk, Wv, bv, qb, kb, vb);
    attn_kernel<<<dim3(128, 2), 256, 0, stream>>>(qb, kb, vb, qp, merged);
    out_gemm<<<dim3(16, 6), 256, 0, stream>>>(merged, Wo, bo, out);
}